// Round 6
// baseline (322.632 us; speedup 1.0000x reference)
//
#include <hip/hip_runtime.h>
#include <hip/hip_bf16.h>
#include <stdint.h>

#define NN 10000
#define NE 250000
#define FEAT 16
#define EMB 32
#define HID 32
#define NV 12
#define EAD 9
#define NG 64
#define EPB 128   // edges per block in edge_msg
#define NCH 25    // nodes per block in computeQ_pack

__device__ __forceinline__ uint32_t bf16rne(float f) {
    uint32_t u = __float_as_uint(f);
    return (u + 0x7fffu + ((u >> 16) & 1u)) >> 16;
}
__device__ __forceinline__ float blo(uint32_t p) { return __uint_as_float(p << 16); }
__device__ __forceinline__ float bhi(uint32_t p) { return __uint_as_float(p & 0xffff0000u); }

// ---------------------------------------------------------------------------
// src/dst degree histograms
// ---------------------------------------------------------------------------
__global__ void edge_stats_kernel(const int* __restrict__ src,
                                  const int* __restrict__ dst,
                                  int* __restrict__ histS,
                                  int* __restrict__ histD) {
    int e = blockIdx.x * blockDim.x + threadIdx.x;
    if (e >= NE) return;
    atomicAdd(&histS[src[e]], 1);
    atomicAdd(&histD[dst[e]], 1);
}

// ---------------------------------------------------------------------------
// Exclusive scan of hist[NN] -> rowStart[NN+1], cursor[NN]. grid=2.
// ---------------------------------------------------------------------------
__global__ __launch_bounds__(1024) void scan_kernel(const int* __restrict__ histS,
                                                    const int* __restrict__ histD,
                                                    int* __restrict__ rowS,
                                                    int* __restrict__ rowD,
                                                    int* __restrict__ curS,
                                                    int* __restrict__ curD) {
    const int* hist = blockIdx.x ? histD : histS;
    int* rowStart   = blockIdx.x ? rowD : rowS;
    int* cursor     = blockIdx.x ? curD : curS;
    __shared__ int part[1024];
    int t = threadIdx.x;
    int base = t * 10;
    int local[10];
    int s = 0;
#pragma unroll
    for (int i = 0; i < 10; ++i) {
        int v = (base + i < NN) ? hist[base + i] : 0;
        local[i] = s;
        s += v;
    }
    part[t] = s;
    __syncthreads();
    for (int off = 1; off < 1024; off <<= 1) {
        int v = (t >= off) ? part[t - off] : 0;
        __syncthreads();
        part[t] += v;
        __syncthreads();
    }
    int pre = (t == 0) ? 0 : part[t - 1];
#pragma unroll
    for (int i = 0; i < 10; ++i) {
        if (base + i < NN) {
            int rs = pre + local[i];
            rowStart[base + i] = rs;
            cursor[base + i] = rs;
        }
    }
    if (t == 1023) rowStart[NN] = part[1023];
}

// ---------------------------------------------------------------------------
// Permute edges to src-sorted order (ea padded to 12 floats); record each
// edge's dst-sorted slot.
// ---------------------------------------------------------------------------
__global__ void scatter_kernel(const float* __restrict__ ea,
                               const int* __restrict__ src,
                               const int* __restrict__ dst,
                               int* __restrict__ cursorS,
                               int* __restrict__ cursorD,
                               float* __restrict__ ea_p,   // [E,12]
                               int* __restrict__ src_s,
                               int* __restrict__ perm_d) {
    int e = blockIdx.x * blockDim.x + threadIdx.x;
    if (e >= NE) return;
    int sv = src[e], dv = dst[e];
    int pos  = atomicAdd(&cursorS[sv], 1);
    int posd = atomicAdd(&cursorD[dv], 1);
    src_s[pos] = sv;
    perm_d[pos] = posd;
#pragma unroll
    for (int j = 0; j < 12; ++j)
        ea_p[(size_t)pos * 12 + j] = (j < EAD) ? ea[(size_t)e * EAD + j] : 0.f;
}

// ---------------------------------------------------------------------------
// Qp[n][kk][o] (kk=0..15) = packed bf16 pair of Q[n,2kk,o] / Q[n,2kk+1,o],
// Q[n,k,o] = sum_i h[n,i]*w2[k, i*32+o]. w2 columns in registers; h rows
// wave-uniform -> scalar loads.
// ---------------------------------------------------------------------------
template <int DIN>
__global__ __launch_bounds__(256) void computeQ_pack_kernel(
    const float* __restrict__ h,    // [N,DIN]
    const float* __restrict__ w2,   // [32, DIN*32]
    uint32_t* __restrict__ Qp)      // [N,16,32]
{
    int t = threadIdx.x;
    int o = t & 31;
    int kk = (blockIdx.y * 256 + t) >> 5;  // 0..15
    float w0[DIN], w1r[DIN];
    const float* wa = w2 + (size_t)(2 * kk) * (DIN * 32) + o;
    const float* wb = w2 + (size_t)(2 * kk + 1) * (DIN * 32) + o;
#pragma unroll
    for (int i = 0; i < DIN; ++i) { w0[i] = wa[i * 32]; w1r[i] = wb[i * 32]; }

    int n0 = blockIdx.x * NCH;
    for (int j = 0; j < NCH; ++j) {
        int n = n0 + j;
        const float* hn = h + (size_t)n * DIN;
        float s0 = 0.f, s1 = 0.f;
#pragma unroll
        for (int i = 0; i < DIN; ++i) {
            float hv = hn[i];
            s0 += hv * w0[i];
            s1 += hv * w1r[i];
        }
        Qp[((size_t)n * 16 + kk) * 32 + o] = (bf16rne(s1) << 16) | bf16rne(s0);
    }
}

// ---------------------------------------------------------------------------
// Qb[n,o] = sum_i h[n,i]*b2[i*32+o]  (fp32 bias row)
// ---------------------------------------------------------------------------
template <int DIN>
__global__ void computeQbias_kernel(const float* __restrict__ h,
                                    const float* __restrict__ b2,
                                    float* __restrict__ Qb) {
    int idx = blockIdx.x * blockDim.x + threadIdx.x;
    if (idx >= NN * 32) return;
    int o = idx & 31;
    int n = idx >> 5;
    const float* hn = h + (size_t)n * DIN;
    float s = 0.f;
#pragma unroll
    for (int i = 0; i < DIN; ++i) s += hn[i] * b2[i * 32 + o];
    Qb[idx] = s;
}

// ---------------------------------------------------------------------------
// Edge messages. 32 lanes/edge: edge-MLP (3x float4), hidden staged via one
// ds_write + broadcast ds_read_b128; Q gathered as bf16 pairs; store at
// dst-sorted slot. No barriers, no atomics.
// ---------------------------------------------------------------------------
__global__ __launch_bounds__(256) void edge_msg_kernel(
    const float* __restrict__ ea_p,   // [E,12]
    const int* __restrict__ src_s,
    const int* __restrict__ perm_d,
    const float* __restrict__ w1,     // [9,32]
    const float* __restrict__ b1,     // [32]
    const uint32_t* __restrict__ Qp,  // [N,16,32]
    const float* __restrict__ Qb,     // [N,32]
    float* __restrict__ msg)          // [E,32] dst-sorted
{
    __shared__ float s_hid[8][32];
    int t = threadIdx.x;
    int o = t & 31;
    int slot = t >> 5;

    float w1r[12];
#pragma unroll
    for (int j = 0; j < 12; ++j) w1r[j] = (j < EAD) ? w1[j * 32 + o] : 0.f;
    float b1r = b1[o];

    int base = blockIdx.x * EPB;
    int eend = min(base + EPB, NE);
    for (int e = base + slot; e < eend; e += 8) {
        const float4* eav = (const float4*)(ea_p + (size_t)e * 12);
        float4 a0 = eav[0], a1 = eav[1], a2 = eav[2];
        float hs = b1r;
        hs += a0.x * w1r[0] + a0.y * w1r[1] + a0.z * w1r[2] + a0.w * w1r[3];
        hs += a1.x * w1r[4] + a1.y * w1r[5] + a1.z * w1r[6] + a1.w * w1r[7];
        hs += a2.x * w1r[8];
        float hd = fmaxf(hs, 0.f);

        s_hid[slot][o] = hd;
        __builtin_amdgcn_wave_barrier();

        int sv = src_s[e];
        const uint32_t* q = Qp + (size_t)sv * 512 + o;
        float m = Qb[(size_t)sv * 32 + o];
        const float4* hq = (const float4*)(&s_hid[slot][0]);
#pragma unroll
        for (int c = 0; c < 8; ++c) {
            float4 hv = hq[c];
            uint32_t qa  = q[(2 * c) * 32];
            uint32_t qb2 = q[(2 * c + 1) * 32];
            m += hv.x * blo(qa) + hv.y * bhi(qa)
               + hv.z * blo(qb2) + hv.w * bhi(qb2);
        }
        msg[(size_t)perm_d[e] * 32 + o] = m;
        __builtin_amdgcn_wave_barrier();
    }
}

// ---------------------------------------------------------------------------
// Wave-per-node segmented mean: lane l sums float4 of row l/8, colgroup l&7;
// 1024B coalesced per wave-iteration; shfl_xor reduce over row-groups; lanes
// 0..7 finish mean + root matmul + bias + ReLU (+ pooling).
// ---------------------------------------------------------------------------
template <int DIN>
__global__ __launch_bounds__(256) void aggregate_kernel(
    const float* __restrict__ msg,
    const int* __restrict__ dRow,
    const float* __restrict__ hin,
    const float* __restrict__ root,
    const float* __restrict__ bias,
    float* __restrict__ hout,
    float* __restrict__ pooled,
    const int* __restrict__ batch,
    float* __restrict__ gcnt)
{
    int t = threadIdx.x;
    int lane = t & 63;
    int n = blockIdx.x * 4 + (t >> 6);
    int rowo = lane >> 3;    // 0..7
    int cg   = lane & 7;     // col group (4 cols)

    int beg = dRow[n], end = dRow[n + 1];
    int deg = end - beg;

    float4 acc = make_float4(0.f, 0.f, 0.f, 0.f);
    for (int r = beg + rowo; r < end; r += 8) {
        float4 v = *(const float4*)(msg + (size_t)r * 32 + cg * 4);
        acc.x += v.x; acc.y += v.y; acc.z += v.z; acc.w += v.w;
    }
#pragma unroll
    for (int off = 8; off < 64; off <<= 1) {
        acc.x += __shfl_xor(acc.x, off);
        acc.y += __shfl_xor(acc.y, off);
        acc.z += __shfl_xor(acc.z, off);
        acc.w += __shfl_xor(acc.w, off);
    }

    if (lane < 8) {
        float inv = 1.0f / fmaxf((float)deg, 1.0f);
        const float4 b4 = *(const float4*)(bias + cg * 4);
        float4 s;
        s.x = acc.x * inv + b4.x;
        s.y = acc.y * inv + b4.y;
        s.z = acc.z * inv + b4.z;
        s.w = acc.w * inv + b4.w;
        const float* h = hin + (size_t)n * DIN;
#pragma unroll
        for (int i = 0; i < DIN; ++i) {
            float hv = h[i];
            float4 r4 = *(const float4*)(root + i * 32 + cg * 4);
            s.x += hv * r4.x; s.y += hv * r4.y; s.z += hv * r4.z; s.w += hv * r4.w;
        }
        s.x = fmaxf(s.x, 0.f); s.y = fmaxf(s.y, 0.f);
        s.z = fmaxf(s.z, 0.f); s.w = fmaxf(s.w, 0.f);
        *(float4*)(hout + (size_t)n * 32 + cg * 4) = s;
        if (pooled) {
            int g = batch[n];
            atomicAdd(&pooled[g * 32 + cg * 4 + 0], s.x);
            atomicAdd(&pooled[g * 32 + cg * 4 + 1], s.y);
            atomicAdd(&pooled[g * 32 + cg * 4 + 2], s.z);
            atomicAdd(&pooled[g * 32 + cg * 4 + 3], s.w);
            if (cg == 0) atomicAdd(&gcnt[g], 1.0f);
        }
    }
}

// ---------------------------------------------------------------------------
// pooled mean -> linear(32,12) -> log_softmax
// ---------------------------------------------------------------------------
__global__ void final_kernel(const float* __restrict__ pooled,
                             const float* __restrict__ gcnt,
                             const float* __restrict__ lin_w,
                             const float* __restrict__ lin_b,
                             float* __restrict__ out) {
    int g = threadIdx.x;
    if (g >= NG) return;
    float inv = 1.0f / fmaxf(gcnt[g], 1.0f);
    float p[HID];
#pragma unroll
    for (int h = 0; h < HID; ++h) p[h] = pooled[g * HID + h] * inv;
    float logits[NV];
    float mx = -1e30f;
#pragma unroll
    for (int v = 0; v < NV; ++v) {
        float s = lin_b[v];
#pragma unroll
        for (int h = 0; h < HID; ++h) s += p[h] * lin_w[h * NV + v];
        logits[v] = s;
        mx = fmaxf(mx, s);
    }
    float se = 0.f;
#pragma unroll
    for (int v = 0; v < NV; ++v) se += expf(logits[v] - mx);
    float lse = mx + logf(se);
#pragma unroll
    for (int v = 0; v < NV; ++v) out[g * NV + v] = logits[v] - lse;
}

// ---------------------------------------------------------------------------
extern "C" void kernel_launch(void* const* d_in, const int* in_sizes, int n_in,
                              void* d_out, int out_size, void* d_ws, size_t ws_size,
                              hipStream_t stream) {
    const float* x        = (const float*)d_in[0];
    const float* ea       = (const float*)d_in[1];
    const int*   eidx     = (const int*)d_in[2];
    const int*   batch    = (const int*)d_in[3];
    const float* nn1_w1   = (const float*)d_in[4];
    const float* nn1_b1   = (const float*)d_in[5];
    const float* nn1_w2   = (const float*)d_in[6];
    const float* nn1_b2   = (const float*)d_in[7];
    const float* root1    = (const float*)d_in[8];
    const float* bias1    = (const float*)d_in[9];
    const float* nn2_w1   = (const float*)d_in[10];
    const float* nn2_b1   = (const float*)d_in[11];
    const float* nn2_w2   = (const float*)d_in[12];
    const float* nn2_b2   = (const float*)d_in[13];
    const float* root2    = (const float*)d_in[14];
    const float* bias2    = (const float*)d_in[15];
    const float* lin_w    = (const float*)d_in[16];
    const float* lin_b    = (const float*)d_in[17];
    float* out = (float*)d_out;

    const int* src = eidx;
    const int* dst = eidx + NE;

    char* base = (char*)d_ws;
    uint32_t* Qp   = (uint32_t*)base;                       // NN*512
    float* msg     = (float*)(Qp + (size_t)NN * 512);       // NE*32
    float* ea_p    = msg + (size_t)NE * 32;                 // NE*12
    float* Qb      = ea_p + (size_t)NE * 12;                // NN*32
    float* h1      = Qb + (size_t)NN * 32;                  // NN*32
    float* h2      = h1 + (size_t)NN * 32;                  // NN*32
    int*   src_s   = (int*)(h2 + (size_t)NN * 32);          // NE
    int*   perm_d  = src_s + NE;                            // NE
    int*   rowS    = perm_d + NE;                           // NN+1
    int*   rowD    = rowS + NN + 1;                         // NN+1
    int*   curS    = rowD + NN + 1;                         // NN
    int*   curD    = curS + NN;                             // NN
    int*   histS   = curD + NN;                             // NN (zeroed from here)
    int*   histD   = histS + NN;                            // NN
    float* pooled  = (float*)(histD + NN);                  // NG*32
    float* gcnt    = pooled + NG * 32;                      // NG
    size_t zero_bytes = ((size_t)NN * 2 + NG * 32 + NG) * 4;

    hipMemsetAsync(histS, 0, zero_bytes, stream);

    // ---- edge sort pre-pass (shared by both convs) ----
    edge_stats_kernel<<<(NE + 255) / 256, 256, 0, stream>>>(src, dst, histS, histD);
    scan_kernel<<<2, 1024, 0, stream>>>(histS, histD, rowS, rowD, curS, curD);
    scatter_kernel<<<(NE + 255) / 256, 256, 0, stream>>>(ea, src, dst, curS, curD,
                                                         ea_p, src_s, perm_d);

    const int edge_grid = (NE + EPB - 1) / EPB;
    dim3 qgrid(NN / NCH, 2);

    // ---- conv1 ----
    computeQ_pack_kernel<FEAT><<<qgrid, 256, 0, stream>>>(x, nn1_w2, Qp);
    computeQbias_kernel<FEAT><<<(NN * 32) / 256, 256, 0, stream>>>(x, nn1_b2, Qb);
    edge_msg_kernel<<<edge_grid, 256, 0, stream>>>(ea_p, src_s, perm_d,
                                                   nn1_w1, nn1_b1, Qp, Qb, msg);
    aggregate_kernel<FEAT><<<NN / 4, 256, 0, stream>>>(
        msg, rowD, x, root1, bias1, h1, nullptr, nullptr, nullptr);

    // ---- conv2 ----
    computeQ_pack_kernel<EMB><<<qgrid, 256, 0, stream>>>(h1, nn2_w2, Qp);
    computeQbias_kernel<EMB><<<(NN * 32) / 256, 256, 0, stream>>>(h1, nn2_b2, Qb);
    edge_msg_kernel<<<edge_grid, 256, 0, stream>>>(ea_p, src_s, perm_d,
                                                   nn2_w1, nn2_b1, Qp, Qb, msg);
    aggregate_kernel<EMB><<<NN / 4, 256, 0, stream>>>(
        msg, rowD, h1, root2, bias2, h2, pooled, batch, gcnt);

    // ---- head ----
    final_kernel<<<1, 64, 0, stream>>>(pooled, gcnt, lin_w, lin_b, out);
}

// Round 7
// 279.160 us; speedup vs baseline: 1.1557x; 1.1557x over previous
//
#include <hip/hip_runtime.h>
#include <hip/hip_bf16.h>
#include <stdint.h>

#define NN 10000
#define NE 250000
#define FEAT 16
#define EMB 32
#define HID 32
#define NV 12
#define EAD 9
#define NG 64
#define EPB 128   // edges per block in edge_agg
#define NCH 25    // nodes per block in computeQ_pack

__device__ __forceinline__ uint32_t bf16rne(float f) {
    uint32_t u = __float_as_uint(f);
    return (u + 0x7fffu + ((u >> 16) & 1u)) >> 16;
}
__device__ __forceinline__ float blo(uint32_t p) { return __uint_as_float(p << 16); }
__device__ __forceinline__ float bhi(uint32_t p) { return __uint_as_float(p & 0xffff0000u); }

// ---------------------------------------------------------------------------
// src/dst degree histograms
// ---------------------------------------------------------------------------
__global__ void edge_stats_kernel(const int* __restrict__ src,
                                  const int* __restrict__ dst,
                                  int* __restrict__ histS,
                                  int* __restrict__ histD) {
    int e = blockIdx.x * blockDim.x + threadIdx.x;
    if (e >= NE) return;
    atomicAdd(&histS[src[e]], 1);
    atomicAdd(&histD[dst[e]], 1);
}

// ---------------------------------------------------------------------------
// Single-block exclusive scan of histS[NN] -> rowS[NN+1], curS[NN]
// ---------------------------------------------------------------------------
__global__ __launch_bounds__(1024) void scan_kernel(const int* __restrict__ hist,
                                                    int* __restrict__ rowStart,
                                                    int* __restrict__ cursor) {
    __shared__ int part[1024];
    int t = threadIdx.x;
    int base = t * 10;
    int local[10];
    int s = 0;
#pragma unroll
    for (int i = 0; i < 10; ++i) {
        int v = (base + i < NN) ? hist[base + i] : 0;
        local[i] = s;
        s += v;
    }
    part[t] = s;
    __syncthreads();
    for (int off = 1; off < 1024; off <<= 1) {
        int v = (t >= off) ? part[t - off] : 0;
        __syncthreads();
        part[t] += v;
        __syncthreads();
    }
    int pre = (t == 0) ? 0 : part[t - 1];
#pragma unroll
    for (int i = 0; i < 10; ++i) {
        if (base + i < NN) {
            int rs = pre + local[i];
            rowStart[base + i] = rs;
            cursor[base + i] = rs;
        }
    }
    if (t == 1023) rowStart[NN] = part[1023];
}

// ---------------------------------------------------------------------------
// Permute edges to src-sorted order (ea padded to 12 floats for float4 loads).
// ---------------------------------------------------------------------------
__global__ void scatter_kernel(const float* __restrict__ ea,
                               const int* __restrict__ src,
                               const int* __restrict__ dst,
                               int* __restrict__ cursorS,
                               float* __restrict__ ea_p,   // [E,12]
                               int* __restrict__ src_s,
                               int* __restrict__ dst_s) {
    int e = blockIdx.x * blockDim.x + threadIdx.x;
    if (e >= NE) return;
    int sv = src[e];
    int pos = atomicAdd(&cursorS[sv], 1);
    src_s[pos] = sv;
    dst_s[pos] = dst[e];
#pragma unroll
    for (int j = 0; j < 12; ++j)
        ea_p[(size_t)pos * 12 + j] = (j < EAD) ? ea[(size_t)e * EAD + j] : 0.f;
}

// ---------------------------------------------------------------------------
// Qp[n][kk][o] (kk=0..15) = packed bf16 pair of Q[n,2kk,o] / Q[n,2kk+1,o],
// Q[n,k,o] = sum_i h[n,i]*w2[k, i*32+o]. w2 columns in registers; h rows
// wave-uniform -> scalar loads.
// ---------------------------------------------------------------------------
template <int DIN>
__global__ __launch_bounds__(256) void computeQ_pack_kernel(
    const float* __restrict__ h,    // [N,DIN]
    const float* __restrict__ w2,   // [32, DIN*32]
    uint32_t* __restrict__ Qp)      // [N,16,32]
{
    int t = threadIdx.x;
    int o = t & 31;
    int kk = (blockIdx.y * 256 + t) >> 5;  // 0..15
    float w0[DIN], w1r[DIN];
    const float* wa = w2 + (size_t)(2 * kk) * (DIN * 32) + o;
    const float* wb = w2 + (size_t)(2 * kk + 1) * (DIN * 32) + o;
#pragma unroll
    for (int i = 0; i < DIN; ++i) { w0[i] = wa[i * 32]; w1r[i] = wb[i * 32]; }

    int n0 = blockIdx.x * NCH;
    for (int j = 0; j < NCH; ++j) {
        int n = n0 + j;
        const float* hn = h + (size_t)n * DIN;
        float s0 = 0.f, s1 = 0.f;
#pragma unroll
        for (int i = 0; i < DIN; ++i) {
            float hv = hn[i];
            s0 += hv * w0[i];
            s1 += hv * w1r[i];
        }
        Qp[((size_t)n * 16 + kk) * 32 + o] = (bf16rne(s1) << 16) | bf16rne(s0);
    }
}

// ---------------------------------------------------------------------------
// Qb[n,o] = sum_i h[n,i]*b2[i*32+o]  (fp32 bias row)
// ---------------------------------------------------------------------------
template <int DIN>
__global__ void computeQbias_kernel(const float* __restrict__ h,
                                    const float* __restrict__ b2,
                                    float* __restrict__ Qb) {
    int idx = blockIdx.x * blockDim.x + threadIdx.x;
    if (idx >= NN * 32) return;
    int o = idx & 31;
    int n = idx >> 5;
    const float* hn = h + (size_t)n * DIN;
    float s = 0.f;
#pragma unroll
    for (int i = 0; i < DIN; ++i) s += hn[i] * b2[i * 32 + o];
    Qb[idx] = s;
}

// ---------------------------------------------------------------------------
// Edge messages fused with scatter-add aggregation. 32 lanes/edge: edge-MLP
// (3x float4), hidden staged via one ds_write + broadcast ds_read_b128; Q
// gathered as bf16 pairs; atomicAdd directly into agg[dst]. No msg roundtrip.
// ---------------------------------------------------------------------------
__global__ __launch_bounds__(256) void edge_agg_kernel(
    const float* __restrict__ ea_p,   // [E,12]
    const int* __restrict__ src_s,
    const int* __restrict__ dst_s,
    const float* __restrict__ w1,     // [9,32]
    const float* __restrict__ b1,     // [32]
    const uint32_t* __restrict__ Qp,  // [N,16,32]
    const float* __restrict__ Qb,     // [N,32]
    float* __restrict__ agg)          // [N,32]
{
    __shared__ float s_hid[8][32];
    int t = threadIdx.x;
    int o = t & 31;
    int slot = t >> 5;

    float w1r[12];
#pragma unroll
    for (int j = 0; j < 12; ++j) w1r[j] = (j < EAD) ? w1[j * 32 + o] : 0.f;
    float b1r = b1[o];

    int base = blockIdx.x * EPB;
    int eend = min(base + EPB, NE);
    for (int e = base + slot; e < eend; e += 8) {
        const float4* eav = (const float4*)(ea_p + (size_t)e * 12);
        float4 a0 = eav[0], a1 = eav[1], a2 = eav[2];
        float hs = b1r;
        hs += a0.x * w1r[0] + a0.y * w1r[1] + a0.z * w1r[2] + a0.w * w1r[3];
        hs += a1.x * w1r[4] + a1.y * w1r[5] + a1.z * w1r[6] + a1.w * w1r[7];
        hs += a2.x * w1r[8];
        float hd = fmaxf(hs, 0.f);

        s_hid[slot][o] = hd;
        __builtin_amdgcn_wave_barrier();

        int sv = src_s[e];
        const uint32_t* q = Qp + (size_t)sv * 512 + o;
        float m = Qb[(size_t)sv * 32 + o];
        const float4* hq = (const float4*)(&s_hid[slot][0]);
#pragma unroll
        for (int c = 0; c < 8; ++c) {
            float4 hv = hq[c];
            uint32_t qa  = q[(2 * c) * 32];
            uint32_t qb2 = q[(2 * c + 1) * 32];
            m += hv.x * blo(qa) + hv.y * bhi(qa)
               + hv.z * blo(qb2) + hv.w * bhi(qb2);
        }
        atomicAdd(&agg[(size_t)dst_s[e] * 32 + o], m);
        __builtin_amdgcn_wave_barrier();
    }
}

// ---------------------------------------------------------------------------
// hout[n,o] = relu(agg[n,o]/max(deg,1) + sum_i hin[n,i]*root[i,o] + bias[o])
// Elementwise; optional fused graph pooling.
// ---------------------------------------------------------------------------
template <int DIN>
__global__ void node_update_kernel(const float* __restrict__ agg,
                                   const int* __restrict__ histD,
                                   const float* __restrict__ hin,
                                   const float* __restrict__ root,
                                   const float* __restrict__ bias,
                                   float* __restrict__ hout,
                                   float* __restrict__ pooled,
                                   const int* __restrict__ batch,
                                   float* __restrict__ gcnt)
{
    int idx = blockIdx.x * blockDim.x + threadIdx.x;
    if (idx >= NN * 32) return;
    int o = idx & 31;
    int n = idx >> 5;
    float s = bias[o] + agg[idx] / fmaxf((float)histD[n], 1.0f);
    const float* h = hin + (size_t)n * DIN;
#pragma unroll
    for (int i = 0; i < DIN; ++i) s += h[i] * root[i * 32 + o];
    s = fmaxf(s, 0.f);
    hout[idx] = s;
    if (pooled) {
        int g = batch[n];
        atomicAdd(&pooled[g * 32 + o], s);
        if (o == 0) atomicAdd(&gcnt[g], 1.0f);
    }
}

// ---------------------------------------------------------------------------
// pooled mean -> linear(32,12) -> log_softmax
// ---------------------------------------------------------------------------
__global__ void final_kernel(const float* __restrict__ pooled,
                             const float* __restrict__ gcnt,
                             const float* __restrict__ lin_w,
                             const float* __restrict__ lin_b,
                             float* __restrict__ out) {
    int g = threadIdx.x;
    if (g >= NG) return;
    float inv = 1.0f / fmaxf(gcnt[g], 1.0f);
    float p[HID];
#pragma unroll
    for (int h = 0; h < HID; ++h) p[h] = pooled[g * HID + h] * inv;
    float logits[NV];
    float mx = -1e30f;
#pragma unroll
    for (int v = 0; v < NV; ++v) {
        float s = lin_b[v];
#pragma unroll
        for (int h = 0; h < HID; ++h) s += p[h] * lin_w[h * NV + v];
        logits[v] = s;
        mx = fmaxf(mx, s);
    }
    float se = 0.f;
#pragma unroll
    for (int v = 0; v < NV; ++v) se += expf(logits[v] - mx);
    float lse = mx + logf(se);
#pragma unroll
    for (int v = 0; v < NV; ++v) out[g * NV + v] = logits[v] - lse;
}

// ---------------------------------------------------------------------------
extern "C" void kernel_launch(void* const* d_in, const int* in_sizes, int n_in,
                              void* d_out, int out_size, void* d_ws, size_t ws_size,
                              hipStream_t stream) {
    const float* x        = (const float*)d_in[0];
    const float* ea       = (const float*)d_in[1];
    const int*   eidx     = (const int*)d_in[2];
    const int*   batch    = (const int*)d_in[3];
    const float* nn1_w1   = (const float*)d_in[4];
    const float* nn1_b1   = (const float*)d_in[5];
    const float* nn1_w2   = (const float*)d_in[6];
    const float* nn1_b2   = (const float*)d_in[7];
    const float* root1    = (const float*)d_in[8];
    const float* bias1    = (const float*)d_in[9];
    const float* nn2_w1   = (const float*)d_in[10];
    const float* nn2_b1   = (const float*)d_in[11];
    const float* nn2_w2   = (const float*)d_in[12];
    const float* nn2_b2   = (const float*)d_in[13];
    const float* root2    = (const float*)d_in[14];
    const float* bias2    = (const float*)d_in[15];
    const float* lin_w    = (const float*)d_in[16];
    const float* lin_b    = (const float*)d_in[17];
    float* out = (float*)d_out;

    const int* src = eidx;
    const int* dst = eidx + NE;

    // workspace: big 16B-aligned arrays first, then ints, then contiguous
    // zeroed region (histS, histD, pooled, gcnt, agg).
    char* base = (char*)d_ws;
    uint32_t* Qp   = (uint32_t*)base;                       // NN*512
    float* ea_p    = (float*)(Qp + (size_t)NN * 512);       // NE*12
    float* Qb      = ea_p + (size_t)NE * 12;                // NN*32
    float* h1      = Qb + (size_t)NN * 32;                  // NN*32
    float* h2      = h1 + (size_t)NN * 32;                  // NN*32
    int*   src_s   = (int*)(h2 + (size_t)NN * 32);          // NE
    int*   dst_s   = src_s + NE;                            // NE
    int*   rowS    = dst_s + NE;                            // NN+1
    int*   curS    = rowS + NN + 1;                         // NN
    int*   histS   = curS + NN;                             // NN (zeroed from here)
    int*   histD   = histS + NN;                            // NN
    float* pooled  = (float*)(histD + NN);                  // NG*32
    float* gcnt    = pooled + NG * 32;                      // NG
    float* agg     = gcnt + NG;                             // NN*32
    size_t zero_bytes = ((size_t)NN * 2 + NG * 32 + NG + (size_t)NN * 32) * 4;

    hipMemsetAsync(histS, 0, zero_bytes, stream);

    // ---- edge sort pre-pass (shared by both convs) ----
    edge_stats_kernel<<<(NE + 255) / 256, 256, 0, stream>>>(src, dst, histS, histD);
    scan_kernel<<<1, 1024, 0, stream>>>(histS, rowS, curS);
    scatter_kernel<<<(NE + 255) / 256, 256, 0, stream>>>(ea, src, dst, curS,
                                                         ea_p, src_s, dst_s);

    const int edge_grid = (NE + EPB - 1) / EPB;
    dim3 qgrid(NN / NCH, 2);

    // ---- conv1 ----
    computeQ_pack_kernel<FEAT><<<qgrid, 256, 0, stream>>>(x, nn1_w2, Qp);
    computeQbias_kernel<FEAT><<<(NN * 32) / 256, 256, 0, stream>>>(x, nn1_b2, Qb);
    edge_agg_kernel<<<edge_grid, 256, 0, stream>>>(ea_p, src_s, dst_s,
                                                   nn1_w1, nn1_b1, Qp, Qb, agg);
    node_update_kernel<FEAT><<<(NN * 32) / 256, 256, 0, stream>>>(
        agg, histD, x, root1, bias1, h1, nullptr, nullptr, nullptr);

    // ---- conv2 ----
    hipMemsetAsync(agg, 0, (size_t)NN * 32 * sizeof(float), stream);
    computeQ_pack_kernel<EMB><<<qgrid, 256, 0, stream>>>(h1, nn2_w2, Qp);
    computeQbias_kernel<EMB><<<(NN * 32) / 256, 256, 0, stream>>>(h1, nn2_b2, Qb);
    edge_agg_kernel<<<edge_grid, 256, 0, stream>>>(ea_p, src_s, dst_s,
                                                   nn2_w1, nn2_b1, Qp, Qb, agg);
    node_update_kernel<EMB><<<(NN * 32) / 256, 256, 0, stream>>>(
        agg, histD, h1, root2, bias2, h2, pooled, batch, gcnt);

    // ---- head ----
    final_kernel<<<1, 64, 0, stream>>>(pooled, gcnt, lin_w, lin_b, out);
}

// Round 8
// 259.371 us; speedup vs baseline: 1.2439x; 1.0763x over previous
//
#include <hip/hip_runtime.h>
#include <hip/hip_bf16.h>
#include <stdint.h>

#define NN 10000
#define NE 250000
#define FEAT 16
#define EMB 32
#define HID 32
#define NV 12
#define EAD 9
#define NG 64
#define EPB 128   // edges per block in edge_agg
#define NCH 25    // nodes per block in computeQ_pack

__device__ __forceinline__ uint32_t bf16rne(float f) {
    uint32_t u = __float_as_uint(f);
    return (u + 0x7fffu + ((u >> 16) & 1u)) >> 16;
}
__device__ __forceinline__ float blo(uint32_t p) { return __uint_as_float(p << 16); }
__device__ __forceinline__ float bhi(uint32_t p) { return __uint_as_float(p & 0xffff0000u); }

// ---------------------------------------------------------------------------
// src/dst degree histograms
// ---------------------------------------------------------------------------
__global__ void edge_stats_kernel(const int* __restrict__ src,
                                  const int* __restrict__ dst,
                                  int* __restrict__ histS,
                                  int* __restrict__ histD) {
    int e = blockIdx.x * blockDim.x + threadIdx.x;
    if (e >= NE) return;
    atomicAdd(&histS[src[e]], 1);
    atomicAdd(&histD[dst[e]], 1);
}

// ---------------------------------------------------------------------------
// Single-block exclusive scan of histS[NN] -> rowS[NN+1], curS[NN]
// ---------------------------------------------------------------------------
__global__ __launch_bounds__(1024) void scan_kernel(const int* __restrict__ hist,
                                                    int* __restrict__ rowStart,
                                                    int* __restrict__ cursor) {
    __shared__ int part[1024];
    int t = threadIdx.x;
    int base = t * 10;
    int local[10];
    int s = 0;
#pragma unroll
    for (int i = 0; i < 10; ++i) {
        int v = (base + i < NN) ? hist[base + i] : 0;
        local[i] = s;
        s += v;
    }
    part[t] = s;
    __syncthreads();
    for (int off = 1; off < 1024; off <<= 1) {
        int v = (t >= off) ? part[t - off] : 0;
        __syncthreads();
        part[t] += v;
        __syncthreads();
    }
    int pre = (t == 0) ? 0 : part[t - 1];
#pragma unroll
    for (int i = 0; i < 10; ++i) {
        if (base + i < NN) {
            int rs = pre + local[i];
            rowStart[base + i] = rs;
            cursor[base + i] = rs;
        }
    }
    if (t == 1023) rowStart[NN] = part[1023];
}

// ---------------------------------------------------------------------------
// Permute edges to src-sorted order (ea padded to 12 floats for float4 loads).
// ---------------------------------------------------------------------------
__global__ void scatter_kernel(const float* __restrict__ ea,
                               const int* __restrict__ src,
                               const int* __restrict__ dst,
                               int* __restrict__ cursorS,
                               float* __restrict__ ea_p,   // [E,12]
                               int* __restrict__ src_s,
                               int* __restrict__ dst_s) {
    int e = blockIdx.x * blockDim.x + threadIdx.x;
    if (e >= NE) return;
    int sv = src[e];
    int pos = atomicAdd(&cursorS[sv], 1);
    src_s[pos] = sv;
    dst_s[pos] = dst[e];
#pragma unroll
    for (int j = 0; j < 12; ++j)
        ea_p[(size_t)pos * 12 + j] = (j < EAD) ? ea[(size_t)e * EAD + j] : 0.f;
}

// ---------------------------------------------------------------------------
// Qp[n][kk][o] (kk=0..15) = packed bf16 pair of Q[n,2kk,o] / Q[n,2kk+1,o],
// Q[n,k,o] = sum_i h[n,i]*w2[k, i*32+o]. w2 columns in registers; h rows
// wave-uniform -> scalar loads.
// ---------------------------------------------------------------------------
template <int DIN>
__global__ __launch_bounds__(256) void computeQ_pack_kernel(
    const float* __restrict__ h,    // [N,DIN]
    const float* __restrict__ w2,   // [32, DIN*32]
    uint32_t* __restrict__ Qp)      // [N,16,32]
{
    int t = threadIdx.x;
    int o = t & 31;
    int kk = (blockIdx.y * 256 + t) >> 5;  // 0..15
    float w0[DIN], w1r[DIN];
    const float* wa = w2 + (size_t)(2 * kk) * (DIN * 32) + o;
    const float* wb = w2 + (size_t)(2 * kk + 1) * (DIN * 32) + o;
#pragma unroll
    for (int i = 0; i < DIN; ++i) { w0[i] = wa[i * 32]; w1r[i] = wb[i * 32]; }

    int n0 = blockIdx.x * NCH;
    for (int j = 0; j < NCH; ++j) {
        int n = n0 + j;
        const float* hn = h + (size_t)n * DIN;
        float s0 = 0.f, s1 = 0.f;
#pragma unroll
        for (int i = 0; i < DIN; ++i) {
            float hv = hn[i];
            s0 += hv * w0[i];
            s1 += hv * w1r[i];
        }
        Qp[((size_t)n * 16 + kk) * 32 + o] = (bf16rne(s1) << 16) | bf16rne(s0);
    }
}

// ---------------------------------------------------------------------------
// Qb[n,o] = sum_i h[n,i]*b2[i*32+o]  (fp32 bias row)
// ---------------------------------------------------------------------------
template <int DIN>
__global__ void computeQbias_kernel(const float* __restrict__ h,
                                    const float* __restrict__ b2,
                                    float* __restrict__ Qb) {
    int idx = blockIdx.x * blockDim.x + threadIdx.x;
    if (idx >= NN * 32) return;
    int o = idx & 31;
    int n = idx >> 5;
    const float* hn = h + (size_t)n * DIN;
    float s = 0.f;
#pragma unroll
    for (int i = 0; i < DIN; ++i) s += hn[i] * b2[i * 32 + o];
    Qb[idx] = s;
}

// ---------------------------------------------------------------------------
// Edge messages fused with scatter-add aggregation. 32 lanes/edge: edge-MLP
// (3x float4), hidden staged via one ds_write + broadcast ds_read_b128; Q
// gathered as bf16 pairs; atomicAdd directly into agg[dst].
// ---------------------------------------------------------------------------
__global__ __launch_bounds__(256) void edge_agg_kernel(
    const float* __restrict__ ea_p,   // [E,12]
    const int* __restrict__ src_s,
    const int* __restrict__ dst_s,
    const float* __restrict__ w1,     // [9,32]
    const float* __restrict__ b1,     // [32]
    const uint32_t* __restrict__ Qp,  // [N,16,32]
    const float* __restrict__ Qb,     // [N,32]
    float* __restrict__ agg)          // [N,32]
{
    __shared__ float s_hid[8][32];
    int t = threadIdx.x;
    int o = t & 31;
    int slot = t >> 5;

    float w1r[12];
#pragma unroll
    for (int j = 0; j < 12; ++j) w1r[j] = (j < EAD) ? w1[j * 32 + o] : 0.f;
    float b1r = b1[o];

    int base = blockIdx.x * EPB;
    int eend = min(base + EPB, NE);
    for (int e = base + slot; e < eend; e += 8) {
        const float4* eav = (const float4*)(ea_p + (size_t)e * 12);
        float4 a0 = eav[0], a1 = eav[1], a2 = eav[2];
        float hs = b1r;
        hs += a0.x * w1r[0] + a0.y * w1r[1] + a0.z * w1r[2] + a0.w * w1r[3];
        hs += a1.x * w1r[4] + a1.y * w1r[5] + a1.z * w1r[6] + a1.w * w1r[7];
        hs += a2.x * w1r[8];
        float hd = fmaxf(hs, 0.f);

        s_hid[slot][o] = hd;
        __builtin_amdgcn_wave_barrier();

        int sv = src_s[e];
        const uint32_t* q = Qp + (size_t)sv * 512 + o;
        float m = Qb[(size_t)sv * 32 + o];
        const float4* hq = (const float4*)(&s_hid[slot][0]);
#pragma unroll
        for (int c = 0; c < 8; ++c) {
            float4 hv = hq[c];
            uint32_t qa  = q[(2 * c) * 32];
            uint32_t qb2 = q[(2 * c + 1) * 32];
            m += hv.x * blo(qa) + hv.y * bhi(qa)
               + hv.z * blo(qb2) + hv.w * bhi(qb2);
        }
        atomicAdd(&agg[(size_t)dst_s[e] * 32 + o], m);
        __builtin_amdgcn_wave_barrier();
    }
}

// ---------------------------------------------------------------------------
// Node update, LDS-tiled: block = 32 nodes. Stage root [DIN,32] and the 32
// h rows in LDS (few coalesced float4s per thread); thread owns (node, 4
// cols): 1 float4 agg load + DIN*4 FMA from LDS + 1 float4 store.
// ---------------------------------------------------------------------------
template <int DIN>
__global__ __launch_bounds__(256) void node_update_kernel(
    const float* __restrict__ agg,
    const int* __restrict__ histD,
    const float* __restrict__ hin,
    const float* __restrict__ root,
    const float* __restrict__ bias,
    float* __restrict__ hout,
    float* __restrict__ pooled,
    const int* __restrict__ batch,
    float* __restrict__ gcnt)
{
    __shared__ float s_root[DIN][32];
    __shared__ float s_h[32][DIN + 1];   // +1 pad: conflict-free row reads
    int t = threadIdx.x;
    int n0 = blockIdx.x * 32;

    // stage root (DIN*8 float4s, coalesced)
    for (int i = t; i < DIN * 8; i += 256)
        ((float4*)&s_root[0][0])[i] = ((const float4*)root)[i];
    // stage 32 h rows (coalesced reads, padded LDS writes)
    for (int idx = t; idx < 32 * DIN; idx += 256) {
        int nl = idx / DIN, i = idx - nl * DIN;
        int n = n0 + nl;
        s_h[nl][i] = (n < NN) ? hin[(size_t)n * DIN + i] : 0.f;
    }
    __syncthreads();

    int nl = t >> 3;       // node within block
    int cg = t & 7;        // 4-col group
    int n = n0 + nl;
    if (n >= NN) return;

    float inv = 1.0f / fmaxf((float)histD[n], 1.0f);
    float4 a4 = *(const float4*)(agg + (size_t)n * 32 + cg * 4);
    float4 b4 = *(const float4*)(bias + cg * 4);
    float4 s;
    s.x = a4.x * inv + b4.x;
    s.y = a4.y * inv + b4.y;
    s.z = a4.z * inv + b4.z;
    s.w = a4.w * inv + b4.w;
#pragma unroll
    for (int i = 0; i < DIN; ++i) {
        float hv = s_h[nl][i];
        float4 r4 = *(const float4*)&s_root[i][cg * 4];
        s.x += hv * r4.x; s.y += hv * r4.y; s.z += hv * r4.z; s.w += hv * r4.w;
    }
    s.x = fmaxf(s.x, 0.f); s.y = fmaxf(s.y, 0.f);
    s.z = fmaxf(s.z, 0.f); s.w = fmaxf(s.w, 0.f);
    *(float4*)(hout + (size_t)n * 32 + cg * 4) = s;

    if (pooled) {
        int g = batch[n];
        atomicAdd(&pooled[g * 32 + cg * 4 + 0], s.x);
        atomicAdd(&pooled[g * 32 + cg * 4 + 1], s.y);
        atomicAdd(&pooled[g * 32 + cg * 4 + 2], s.z);
        atomicAdd(&pooled[g * 32 + cg * 4 + 3], s.w);
        if (cg == 0) atomicAdd(&gcnt[g], 1.0f);
    }
}

// ---------------------------------------------------------------------------
// pooled mean -> linear(32,12) -> log_softmax
// ---------------------------------------------------------------------------
__global__ void final_kernel(const float* __restrict__ pooled,
                             const float* __restrict__ gcnt,
                             const float* __restrict__ lin_w,
                             const float* __restrict__ lin_b,
                             float* __restrict__ out) {
    int g = threadIdx.x;
    if (g >= NG) return;
    float inv = 1.0f / fmaxf(gcnt[g], 1.0f);
    float p[HID];
#pragma unroll
    for (int h = 0; h < HID; ++h) p[h] = pooled[g * HID + h] * inv;
    float logits[NV];
    float mx = -1e30f;
#pragma unroll
    for (int v = 0; v < NV; ++v) {
        float s = lin_b[v];
#pragma unroll
        for (int h = 0; h < HID; ++h) s += p[h] * lin_w[h * NV + v];
        logits[v] = s;
        mx = fmaxf(mx, s);
    }
    float se = 0.f;
#pragma unroll
    for (int v = 0; v < NV; ++v) se += expf(logits[v] - mx);
    float lse = mx + logf(se);
#pragma unroll
    for (int v = 0; v < NV; ++v) out[g * NV + v] = logits[v] - lse;
}

// ---------------------------------------------------------------------------
extern "C" void kernel_launch(void* const* d_in, const int* in_sizes, int n_in,
                              void* d_out, int out_size, void* d_ws, size_t ws_size,
                              hipStream_t stream) {
    const float* x        = (const float*)d_in[0];
    const float* ea       = (const float*)d_in[1];
    const int*   eidx     = (const int*)d_in[2];
    const int*   batch    = (const int*)d_in[3];
    const float* nn1_w1   = (const float*)d_in[4];
    const float* nn1_b1   = (const float*)d_in[5];
    const float* nn1_w2   = (const float*)d_in[6];
    const float* nn1_b2   = (const float*)d_in[7];
    const float* root1    = (const float*)d_in[8];
    const float* bias1    = (const float*)d_in[9];
    const float* nn2_w1   = (const float*)d_in[10];
    const float* nn2_b1   = (const float*)d_in[11];
    const float* nn2_w2   = (const float*)d_in[12];
    const float* nn2_b2   = (const float*)d_in[13];
    const float* root2    = (const float*)d_in[14];
    const float* bias2    = (const float*)d_in[15];
    const float* lin_w    = (const float*)d_in[16];
    const float* lin_b    = (const float*)d_in[17];
    float* out = (float*)d_out;

    const int* src = eidx;
    const int* dst = eidx + NE;

    // workspace: 16B-aligned float arrays first (agg before any odd-sized int
    // arrays so float4 access stays aligned), then ints, then small pooled.
    char* base = (char*)d_ws;
    uint32_t* Qp   = (uint32_t*)base;                       // NN*512
    float* ea_p    = (float*)(Qp + (size_t)NN * 512);       // NE*12
    float* Qb      = ea_p + (size_t)NE * 12;                // NN*32
    float* h1      = Qb + (size_t)NN * 32;                  // NN*32
    float* h2      = h1 + (size_t)NN * 32;                  // NN*32
    float* agg     = h2 + (size_t)NN * 32;                  // NN*32 (zeroed)
    int*   src_s   = (int*)(agg + (size_t)NN * 32);         // NE
    int*   dst_s   = src_s + NE;                            // NE
    int*   rowS    = dst_s + NE;                            // NN+1
    int*   curS    = rowS + NN + 1;                         // NN
    int*   histS   = curS + NN;                             // NN (zeroed from here)
    int*   histD   = histS + NN;                            // NN
    float* pooled  = (float*)(histD + NN);                  // NG*32
    float* gcnt    = pooled + NG * 32;                      // NG
    size_t zero_bytes = ((size_t)NN * 2 + NG * 32 + NG) * 4;

    hipMemsetAsync(agg, 0, (size_t)NN * 32 * sizeof(float), stream);
    hipMemsetAsync(histS, 0, zero_bytes, stream);

    // ---- edge sort pre-pass (shared by both convs) ----
    edge_stats_kernel<<<(NE + 255) / 256, 256, 0, stream>>>(src, dst, histS, histD);
    scan_kernel<<<1, 1024, 0, stream>>>(histS, rowS, curS);
    scatter_kernel<<<(NE + 255) / 256, 256, 0, stream>>>(ea, src, dst, curS,
                                                         ea_p, src_s, dst_s);

    const int edge_grid = (NE + EPB - 1) / EPB;
    const int node_grid = (NN + 31) / 32;
    dim3 qgrid(NN / NCH, 2);

    // ---- conv1 ----
    computeQ_pack_kernel<FEAT><<<qgrid, 256, 0, stream>>>(x, nn1_w2, Qp);
    computeQbias_kernel<FEAT><<<(NN * 32) / 256, 256, 0, stream>>>(x, nn1_b2, Qb);
    edge_agg_kernel<<<edge_grid, 256, 0, stream>>>(ea_p, src_s, dst_s,
                                                   nn1_w1, nn1_b1, Qp, Qb, agg);
    node_update_kernel<FEAT><<<node_grid, 256, 0, stream>>>(
        agg, histD, x, root1, bias1, h1, nullptr, nullptr, nullptr);

    // ---- conv2 ----
    hipMemsetAsync(agg, 0, (size_t)NN * 32 * sizeof(float), stream);
    computeQ_pack_kernel<EMB><<<qgrid, 256, 0, stream>>>(h1, nn2_w2, Qp);
    computeQbias_kernel<EMB><<<(NN * 32) / 256, 256, 0, stream>>>(h1, nn2_b2, Qb);
    edge_agg_kernel<<<edge_grid, 256, 0, stream>>>(ea_p, src_s, dst_s,
                                                   nn2_w1, nn2_b1, Qp, Qb, agg);
    node_update_kernel<EMB><<<node_grid, 256, 0, stream>>>(
        agg, histD, h1, root2, bias2, h2, pooled, batch, gcnt);

    // ---- head ----
    final_kernel<<<1, 64, 0, stream>>>(pooled, gcnt, lin_w, lin_b, out);
}